// Round 2
// baseline (575.816 us; speedup 1.0000x reference)
//
#include <hip/hip_runtime.h>

typedef short bf16x8 __attribute__((ext_vector_type(8)));
typedef float f32x4 __attribute__((ext_vector_type(4)));

__device__ __forceinline__ unsigned short f2b(float f) {
  union { float f; unsigned int u; } c; c.f = f;
  unsigned int u = c.u + 0x7fffu + ((c.u >> 16) & 1u);
  return (unsigned short)(u >> 16);
}

__device__ __forceinline__ void ld_g2l16(const void* g, void* l) {
  __builtin_amdgcn_global_load_lds(
      (__attribute__((address_space(1))) void*)(void*)g,
      (__attribute__((address_space(3))) void*)l, 16, 0, 0);
}

// ---------------- conversions ----------------

__global__ __launch_bounds__(256) void k_cvt(const float* __restrict__ in,
                                             unsigned short* __restrict__ out, int n) {
  int i = (blockIdx.x * 256 + threadIdx.x) * 4;
  const int stride = gridDim.x * 256 * 4;
  for (; i < n; i += stride) {
    const float4 v = *(const float4*)(in + i);
    unsigned short o0 = f2b(v.x), o1 = f2b(v.y), o2 = f2b(v.z), o3 = f2b(v.w);
    ushort4 o; o.x = o0; o.y = o1; o.z = o2; o.w = o3;
    *(ushort4*)(out + i) = o;
  }
}

// W [K][N] fp32  ->  Wt [N][K] bf16
__global__ __launch_bounds__(256) void k_tw(const float* __restrict__ W,
                                            unsigned short* __restrict__ Wt, int K, int N) {
  __shared__ float tile[32][33];
  const int nb = blockIdx.x * 32, kb = blockIdx.y * 32;
  const int tx = threadIdx.x & 31, ty = threadIdx.x >> 5;
#pragma unroll
  for (int i = 0; i < 32; i += 8)
    tile[ty + i][tx] = W[(size_t)(kb + ty + i) * N + nb + tx];
  __syncthreads();
#pragma unroll
  for (int i = 0; i < 32; i += 8)
    Wt[(size_t)(nb + ty + i) * K + kb + tx] = f2b(tile[tx][ty + i]);
}

// v [4096][512] bf16 -> vT [8][128][2048] bf16  (per (b,kv): [s][d] -> [d][s])
__global__ __launch_bounds__(256) void k_tv(const unsigned short* __restrict__ v,
                                            unsigned short* __restrict__ vT) {
  __shared__ unsigned short tile[32][33];
  const int sb = blockIdx.x * 32, db = blockIdx.y * 32;
  const int ob = blockIdx.z, b = ob >> 2, kvh = ob & 3;
  const int tx = threadIdx.x & 31, ty = threadIdx.x >> 5;
#pragma unroll
  for (int i = 0; i < 32; i += 8)
    tile[ty + i][tx] = v[(size_t)(b * 2048 + sb + ty + i) * 512 + kvh * 128 + db + tx];
  __syncthreads();
#pragma unroll
  for (int i = 0; i < 32; i += 8)
    vT[(size_t)ob * 262144 + (size_t)(db + ty + i) * 2048 + sb + tx] = tile[tx][ty + i];
}

// ---------------- GEMM: C[M][N] = A[M][K] @ Bt[N][K]^T + bias ----------------
// 128x128 tile, BK=64, 4 waves (2x2 of 64x64), global_load_lds staging with
// pre-swizzled source (chunk ^= row&7) for conflict-free ds_read_b128.

template <int OUT_F32>
__global__ __launch_bounds__(256) void gemm_bt(const unsigned short* __restrict__ A,
                                               const unsigned short* __restrict__ Bt,
                                               const float* __restrict__ bias,
                                               void* __restrict__ Cout,
                                               int M, int N, int K) {
  __shared__ unsigned short As[8192] __attribute__((aligned(16)));
  __shared__ unsigned short Bs[8192] __attribute__((aligned(16)));
  const int t = threadIdx.x, w = t >> 6, lane = t & 63;
  const int wr = w >> 1, wc = w & 1;
  const int bm = blockIdx.y, bn = blockIdx.x;

  f32x4 acc[4][4] = {};

  const int srow = w * 8 + (lane >> 3);
  const int scol = ((lane & 7) ^ (lane >> 3)) << 3;
  const unsigned short* Ap = A + (size_t)(bm * 128 + srow) * K + scol;
  const unsigned short* Bp = Bt + (size_t)(bn * 128 + srow) * K + scol;
  unsigned short* Ad = &As[(w * 64 + lane) * 8];
  unsigned short* Bd = &Bs[(w * 64 + lane) * 8];

  const int nkt = K >> 6;
  for (int kt = 0; kt < nkt; ++kt) {
#pragma unroll
    for (int i = 0; i < 4; ++i) {
      ld_g2l16(Ap + (size_t)i * 32 * K, Ad + i * 2048);
      ld_g2l16(Bp + (size_t)i * 32 * K, Bd + i * 2048);
    }
    Ap += 64; Bp += 64;
    __syncthreads();
#pragma unroll
    for (int kk = 0; kk < 2; ++kk) {
      bf16x8 av[4], bv[4];
#pragma unroll
      for (int m = 0; m < 4; ++m) {
        int r = wr * 64 + m * 16 + (lane & 15);
        int c = ((kk << 2) + (lane >> 4)) ^ (r & 7);
        av[m] = *(const bf16x8*)&As[r * 64 + c * 8];
      }
#pragma unroll
      for (int n = 0; n < 4; ++n) {
        int r = wc * 64 + n * 16 + (lane & 15);
        int c = ((kk << 2) + (lane >> 4)) ^ (r & 7);
        bv[n] = *(const bf16x8*)&Bs[r * 64 + c * 8];
      }
#pragma unroll
      for (int m = 0; m < 4; ++m)
#pragma unroll
        for (int n = 0; n < 4; ++n)
          acc[m][n] = __builtin_amdgcn_mfma_f32_16x16x32_bf16(av[m], bv[n], acc[m][n], 0, 0, 0);
    }
    __syncthreads();
  }

  const int row0 = bm * 128 + wr * 64 + ((lane >> 4) << 2);
  const int col0 = bn * 128 + wc * 64 + (lane & 15);
#pragma unroll
  for (int n = 0; n < 4; ++n) {
    const int c = col0 + n * 16;
    const float bb = bias[c];
#pragma unroll
    for (int m = 0; m < 4; ++m) {
#pragma unroll
      for (int j = 0; j < 4; ++j) {
        const float v = acc[m][n][j] + bb;
        const size_t idx = (size_t)(row0 + m * 16 + j) * N + c;
        if (OUT_F32) ((float*)Cout)[idx] = v;
        else ((unsigned short*)Cout)[idx] = f2b(v);
      }
    }
  }
}

// ---------------- flash attention (GQA) ----------------
// grid (16 q-tiles, 32 b*h). Block: 4 waves x 32 q-rows = 128 q-rows.
// KBLK=64. Q in registers; K/Vt/P tiles in 48KB LDS, XOR-swizzled.

__global__ __launch_bounds__(256) void flash_gqa(const unsigned short* __restrict__ Q,
                                                 const unsigned short* __restrict__ Kx,
                                                 const unsigned short* __restrict__ Vt,
                                                 unsigned short* __restrict__ Oa) {
  __shared__ unsigned short smem[24576] __attribute__((aligned(16)));
  unsigned short* const Qs = smem;          // phase 0: [128][128]
  unsigned short* const Ks = smem;          // [64][128]
  unsigned short* const Vs = smem + 8192;   // [128][64]
  unsigned short* const Ps = smem + 16384;  // [128][64]

  const int t = threadIdx.x, w = t >> 6, lane = t & 63;
  const int qt = blockIdx.x, bh = blockIdx.y;
  const int b = bh >> 4, h = bh & 15, kvh = h >> 2;

  const unsigned short* Qg = Q + (size_t)(b * 2048 + qt * 128) * 2048 + h * 128;
  const unsigned short* Kg = Kx + (size_t)(b * 2048) * 512 + kvh * 128;
  const unsigned short* Vg = Vt + (size_t)(b * 4 + kvh) * 262144;

  // stage Q [128][128] (16 chunks/row, chunk ^= row&15)
  {
    const int row = w * 4 + (lane >> 4);
    const int sc = ((lane & 15) ^ row) << 3;
    const unsigned short* src = Qg + (size_t)row * 2048 + sc;
    unsigned short* dst = &Qs[(w * 64 + lane) * 8];
#pragma unroll
    for (int i = 0; i < 8; ++i) ld_g2l16(src + (size_t)i * 32768, dst + i * 2048);
  }
  __syncthreads();
  bf16x8 qf[2][4];
#pragma unroll
  for (int mi = 0; mi < 2; ++mi) {
    const int r = w * 32 + mi * 16 + (lane & 15);
#pragma unroll
    for (int kk = 0; kk < 4; ++kk) {
      const int c = ((kk << 2) + (lane >> 4)) ^ (lane & 15);
      qf[mi][kk] = *(const bf16x8*)&Qs[r * 128 + c * 8];
    }
  }
  __syncthreads();

  const float SC2 = 0.1275174246f;  // (1/sqrt(128)) * log2(e)
  float m_run[2][4], l_run[2][4];
#pragma unroll
  for (int mi = 0; mi < 2; ++mi)
#pragma unroll
    for (int j = 0; j < 4; ++j) { m_run[mi][j] = -1e30f; l_run[mi][j] = 0.f; }
  f32x4 oacc[2][8] = {};

  const int krow = w * 4 + (lane >> 4);
  const int ksc = ((lane & 15) ^ krow) << 3;
  const int vrow = w * 8 + (lane >> 3);
  const int vsc = ((lane & 7) ^ (lane >> 3)) << 3;
  unsigned short* Kd = &Ks[(w * 64 + lane) * 8];
  unsigned short* Vd = &Vs[(w * 64 + lane) * 8];

  for (int kt = 0; kt < 32; ++kt) {
    const unsigned short* ks = Kg + (size_t)(kt * 64 + krow) * 512 + ksc;
    const unsigned short* vs = Vg + (size_t)vrow * 2048 + kt * 64 + vsc;
#pragma unroll
    for (int i = 0; i < 4; ++i) {
      ld_g2l16(ks + (size_t)i * 8192, Kd + i * 2048);
      ld_g2l16(vs + (size_t)i * 65536, Vd + i * 2048);
    }
    __syncthreads();

    // S = Q K^T
    f32x4 sac[2][4] = {};
#pragma unroll
    for (int kk = 0; kk < 4; ++kk) {
      bf16x8 kf[4];
#pragma unroll
      for (int n = 0; n < 4; ++n) {
        const int r = n * 16 + (lane & 15);
        const int c = ((kk << 2) + (lane >> 4)) ^ (lane & 15);
        kf[n] = *(const bf16x8*)&Ks[r * 128 + c * 8];
      }
#pragma unroll
      for (int mi = 0; mi < 2; ++mi)
#pragma unroll
        for (int n = 0; n < 4; ++n)
          sac[mi][n] = __builtin_amdgcn_mfma_f32_16x16x32_bf16(qf[mi][kk], kf[n], sac[mi][n], 0, 0, 0);
    }

    // online softmax in exp2 domain
#pragma unroll
    for (int mi = 0; mi < 2; ++mi) {
#pragma unroll
      for (int n = 0; n < 4; ++n)
#pragma unroll
        for (int j = 0; j < 4; ++j) sac[mi][n][j] *= SC2;
#pragma unroll
      for (int j = 0; j < 4; ++j) {
        float tm = fmaxf(fmaxf(sac[mi][0][j], sac[mi][1][j]),
                         fmaxf(sac[mi][2][j], sac[mi][3][j]));
#pragma unroll
        for (int off = 1; off < 16; off <<= 1) tm = fmaxf(tm, __shfl_xor(tm, off, 64));
        const float mn = fmaxf(m_run[mi][j], tm);
        const float corr = exp2f(m_run[mi][j] - mn);
        m_run[mi][j] = mn;
        float rs = 0.f;
#pragma unroll
        for (int n = 0; n < 4; ++n) {
          const float p = exp2f(sac[mi][n][j] - mn);
          sac[mi][n][j] = p;
          rs += p;
        }
#pragma unroll
        for (int off = 1; off < 16; off <<= 1) rs += __shfl_xor(rs, off, 64);
        l_run[mi][j] = l_run[mi][j] * corr + rs;
#pragma unroll
        for (int di = 0; di < 8; ++di) oacc[mi][di][j] *= corr;
      }
    }

    // write P tile [128][64] bf16 (chunk ^= row&7)
#pragma unroll
    for (int mi = 0; mi < 2; ++mi) {
      const int rbase = w * 32 + mi * 16 + ((lane >> 4) << 2);
#pragma unroll
      for (int j = 0; j < 4; ++j) {
        const int r = rbase + j;
#pragma unroll
        for (int n = 0; n < 4; ++n) {
          const int col = n * 16 + (lane & 15);
          Ps[r * 64 + (((col >> 3) ^ (r & 7)) << 3) + (lane & 7)] = f2b(sac[mi][n][j]);
        }
      }
    }
    __syncthreads();

    // O += P @ V
#pragma unroll
    for (int kk = 0; kk < 2; ++kk) {
      bf16x8 pf[2];
#pragma unroll
      for (int mi = 0; mi < 2; ++mi) {
        const int r = w * 32 + mi * 16 + (lane & 15);
        const int c = ((kk << 2) + (lane >> 4)) ^ (lane & 7);
        pf[mi] = *(const bf16x8*)&Ps[r * 64 + c * 8];
      }
#pragma unroll
      for (int di = 0; di < 8; ++di) {
        const int r = di * 16 + (lane & 15);
        const int c = ((kk << 2) + (lane >> 4)) ^ (lane & 7);
        const bf16x8 vf = *(const bf16x8*)&Vs[r * 64 + c * 8];
#pragma unroll
        for (int mi = 0; mi < 2; ++mi)
          oacc[mi][di] = __builtin_amdgcn_mfma_f32_16x16x32_bf16(pf[mi], vf, oacc[mi][di], 0, 0, 0);
      }
    }
    __syncthreads();
  }

  // epilogue: O /= l, store bf16
#pragma unroll
  for (int mi = 0; mi < 2; ++mi) {
    const int rbase = b * 2048 + qt * 128 + w * 32 + mi * 16 + ((lane >> 4) << 2);
#pragma unroll
    for (int j = 0; j < 4; ++j) {
      const float inv = 1.0f / l_run[mi][j];
#pragma unroll
      for (int di = 0; di < 8; ++di) {
        const int col = h * 128 + di * 16 + (lane & 15);
        Oa[(size_t)(rbase + j) * 2048 + col] = f2b(oacc[mi][di][j] * inv);
      }
    }
  }
}

// ---------------- launch ----------------

extern "C" void kernel_launch(void* const* d_in, const int* in_sizes, int n_in,
                              void* d_out, int out_size, void* d_ws, size_t ws_size,
                              hipStream_t stream) {
  (void)in_sizes; (void)n_in; (void)out_size; (void)ws_size;
  const float* x  = (const float*)d_in[0];
  const float* wq = (const float*)d_in[1];
  const float* bq = (const float*)d_in[2];
  const float* wk = (const float*)d_in[3];
  const float* bk = (const float*)d_in[4];
  const float* wv = (const float*)d_in[5];
  const float* bv = (const float*)d_in[6];
  const float* wo = (const float*)d_in[7];
  const float* bo = (const float*)d_in[8];

  char* ws = (char*)d_ws;
  unsigned short* xb  = (unsigned short*)(ws);              // [4096][2048] bf16 (reused as attn-out)
  unsigned short* qb  = (unsigned short*)(ws + 16777216);   // [4096][2048]
  unsigned short* kb  = (unsigned short*)(ws + 33554432);   // [4096][512]
  unsigned short* vb  = (unsigned short*)(ws + 37748736);   // [4096][512]
  unsigned short* vT  = (unsigned short*)(ws + 41943040);   // [8][128][2048]
  unsigned short* wqT = (unsigned short*)(ws + 46137344);   // [2048][2048]
  unsigned short* wkT = (unsigned short*)(ws + 54525952);   // [512][2048]
  unsigned short* wvT = (unsigned short*)(ws + 56623104);   // [512][2048]
  unsigned short* woT = (unsigned short*)(ws + 58720256);   // [2048][2048]

  k_cvt<<<4096, 256, 0, stream>>>(x, xb, 4096 * 2048);
  k_tw<<<dim3(64, 64), 256, 0, stream>>>(wq, wqT, 2048, 2048);
  k_tw<<<dim3(16, 64), 256, 0, stream>>>(wk, wkT, 2048, 512);
  k_tw<<<dim3(16, 64), 256, 0, stream>>>(wv, wvT, 2048, 512);
  k_tw<<<dim3(64, 64), 256, 0, stream>>>(wo, woT, 2048, 2048);

  gemm_bt<0><<<dim3(16, 32), 256, 0, stream>>>(xb, wqT, bq, qb, 4096, 2048, 2048);
  gemm_bt<0><<<dim3(4, 32), 256, 0, stream>>>(xb, wkT, bk, kb, 4096, 512, 2048);
  gemm_bt<0><<<dim3(4, 32), 256, 0, stream>>>(xb, wvT, bv, vb, 4096, 512, 2048);

  k_tv<<<dim3(64, 4, 8), 256, 0, stream>>>(vb, vT);

  unsigned short* ao = xb;  // reuse x-bf16 buffer for attention output
  flash_gqa<<<dim3(16, 32), 256, 0, stream>>>(qb, kb, vT, ao);

  gemm_bt<1><<<dim3(16, 32), 256, 0, stream>>>(ao, woT, bo, (float*)d_out, 4096, 2048, 2048);
}

// Round 3
// 425.805 us; speedup vs baseline: 1.3523x; 1.3523x over previous
//
#include <hip/hip_runtime.h>

typedef short bf16x8 __attribute__((ext_vector_type(8)));
typedef float f32x4 __attribute__((ext_vector_type(4)));

__device__ __forceinline__ unsigned short f2b(float f) {
  union { float f; unsigned int u; } c; c.f = f;
  unsigned int u = c.u + 0x7fffu + ((c.u >> 16) & 1u);
  return (unsigned short)(u >> 16);
}

__device__ __forceinline__ void ld_g2l16(const void* g, void* l) {
  __builtin_amdgcn_global_load_lds(
      (__attribute__((address_space(1))) void*)(void*)g,
      (__attribute__((address_space(3))) void*)l, 16, 0, 0);
}

// ---------------- conversions ----------------

__global__ __launch_bounds__(256) void k_cvt(const float* __restrict__ in,
                                             unsigned short* __restrict__ out, int n) {
  int i = (blockIdx.x * 256 + threadIdx.x) * 4;
  const int stride = gridDim.x * 256 * 4;
  for (; i < n; i += stride) {
    const float4 v = *(const float4*)(in + i);
    unsigned short o0 = f2b(v.x), o1 = f2b(v.y), o2 = f2b(v.z), o3 = f2b(v.w);
    ushort4 o; o.x = o0; o.y = o1; o.z = o2; o.w = o3;
    *(ushort4*)(out + i) = o;
  }
}

// W [K][N] fp32  ->  Wt [N][K] bf16
__global__ __launch_bounds__(256) void k_tw(const float* __restrict__ W,
                                            unsigned short* __restrict__ Wt, int K, int N) {
  __shared__ float tile[32][33];
  const int nb = blockIdx.x * 32, kb = blockIdx.y * 32;
  const int tx = threadIdx.x & 31, ty = threadIdx.x >> 5;
#pragma unroll
  for (int i = 0; i < 32; i += 8)
    tile[ty + i][tx] = W[(size_t)(kb + ty + i) * N + nb + tx];
  __syncthreads();
#pragma unroll
  for (int i = 0; i < 32; i += 8)
    Wt[(size_t)(nb + ty + i) * K + kb + tx] = f2b(tile[tx][ty + i]);
}

// kv [4096][1024] bf16 (v at col 512+) -> vT [8][128][2048] bf16
__global__ __launch_bounds__(256) void k_tv(const unsigned short* __restrict__ v,
                                            unsigned short* __restrict__ vT) {
  __shared__ unsigned short tile[32][33];
  const int sb = blockIdx.x * 32, db = blockIdx.y * 32;
  const int ob = blockIdx.z, b = ob >> 2, kvh = ob & 3;
  const int tx = threadIdx.x & 31, ty = threadIdx.x >> 5;
#pragma unroll
  for (int i = 0; i < 32; i += 8)
    tile[ty + i][tx] = v[(size_t)(b * 2048 + sb + ty + i) * 1024 + 512 + kvh * 128 + db + tx];
  __syncthreads();
#pragma unroll
  for (int i = 0; i < 32; i += 8)
    vT[(size_t)ob * 262144 + (size_t)(db + ty + i) * 2048 + sb + tx] = tile[tx][ty + i];
}

// ---------------- GEMM: C[M][N] = A[M][K] @ Bt[N][K]^T + bias ----------------
// 128x128 tile, BK=64, 4 waves (2x2 of 64x64), global_load_lds staging with
// pre-swizzled source (chunk ^= row&7) for conflict-free ds_read_b128.
// bias select: col < nsplit -> bias[col], else bias2[col-nsplit].

template <int OUT_F32>
__global__ __launch_bounds__(256) void gemm_bt(const unsigned short* __restrict__ A,
                                               const unsigned short* __restrict__ Bt,
                                               const float* __restrict__ bias,
                                               const float* __restrict__ bias2,
                                               int nsplit,
                                               void* __restrict__ Cout,
                                               int M, int N, int K) {
  __shared__ unsigned short As[8192] __attribute__((aligned(16)));
  __shared__ unsigned short Bs[8192] __attribute__((aligned(16)));
  const int t = threadIdx.x, w = t >> 6, lane = t & 63;
  const int wr = w >> 1, wc = w & 1;
  const int bm = blockIdx.y, bn = blockIdx.x;

  f32x4 acc[4][4] = {};

  const int srow = w * 8 + (lane >> 3);
  const int scol = ((lane & 7) ^ (lane >> 3)) << 3;
  const unsigned short* Ap = A + (size_t)(bm * 128 + srow) * K + scol;
  const unsigned short* Bp = Bt + (size_t)(bn * 128 + srow) * K + scol;
  unsigned short* Ad = &As[(w * 64 + lane) * 8];
  unsigned short* Bd = &Bs[(w * 64 + lane) * 8];

  const int nkt = K >> 6;
  for (int kt = 0; kt < nkt; ++kt) {
#pragma unroll
    for (int i = 0; i < 4; ++i) {
      ld_g2l16(Ap + (size_t)i * 32 * K, Ad + i * 2048);
      ld_g2l16(Bp + (size_t)i * 32 * K, Bd + i * 2048);
    }
    Ap += 64; Bp += 64;
    __syncthreads();
#pragma unroll
    for (int kk = 0; kk < 2; ++kk) {
      bf16x8 av[4], bv[4];
#pragma unroll
      for (int m = 0; m < 4; ++m) {
        int r = wr * 64 + m * 16 + (lane & 15);
        int c = ((kk << 2) + (lane >> 4)) ^ (r & 7);
        av[m] = *(const bf16x8*)&As[r * 64 + c * 8];
      }
#pragma unroll
      for (int n = 0; n < 4; ++n) {
        int r = wc * 64 + n * 16 + (lane & 15);
        int c = ((kk << 2) + (lane >> 4)) ^ (r & 7);
        bv[n] = *(const bf16x8*)&Bs[r * 64 + c * 8];
      }
#pragma unroll
      for (int m = 0; m < 4; ++m)
#pragma unroll
        for (int n = 0; n < 4; ++n)
          acc[m][n] = __builtin_amdgcn_mfma_f32_16x16x32_bf16(av[m], bv[n], acc[m][n], 0, 0, 0);
    }
    __syncthreads();
  }

  const int row0 = bm * 128 + wr * 64 + ((lane >> 4) << 2);
  const int col0 = bn * 128 + wc * 64 + (lane & 15);
#pragma unroll
  for (int n = 0; n < 4; ++n) {
    const int c = col0 + n * 16;
    const float bb = (c < nsplit) ? bias[c] : bias2[c - nsplit];
#pragma unroll
    for (int m = 0; m < 4; ++m) {
#pragma unroll
      for (int j = 0; j < 4; ++j) {
        const float v = acc[m][n][j] + bb;
        const size_t idx = (size_t)(row0 + m * 16 + j) * N + c;
        if (OUT_F32) ((float*)Cout)[idx] = v;
        else ((unsigned short*)Cout)[idx] = f2b(v);
      }
    }
  }
}

// ---------------- flash attention (GQA) ----------------
// grid (32 q-tiles of 64 rows, 32 b*h). Block: 4 waves x 16 q-rows.
// KBLK=64. Q in registers; K/Vt/P tiles in 40KB LDS, XOR-swizzled.
// K matrix is kvb [4096][1024] (cols kvh*128..); V^T is vT [8][128][2048].

__global__ __launch_bounds__(256, 4) void flash_gqa(const unsigned short* __restrict__ Q,
                                                    const unsigned short* __restrict__ Kx,
                                                    const unsigned short* __restrict__ Vt,
                                                    unsigned short* __restrict__ Oa) {
  __shared__ unsigned short smem[20480] __attribute__((aligned(16)));
  unsigned short* const Qs = smem;          // phase 0: [64][128]
  unsigned short* const Ks = smem;          // [64][128]
  unsigned short* const Vs = smem + 8192;   // [128][64]
  unsigned short* const Ps = smem + 16384;  // [64][64]

  const int t = threadIdx.x, w = t >> 6, lane = t & 63;
  const int qt = blockIdx.x, bh = blockIdx.y;
  const int b = bh >> 4, h = bh & 15, kvh = h >> 2;

  const unsigned short* Qg = Q + (size_t)(b * 2048 + qt * 64) * 2048 + h * 128;
  const unsigned short* Kg = Kx + (size_t)(b * 2048) * 1024 + kvh * 128;
  const unsigned short* Vg = Vt + (size_t)(b * 4 + kvh) * 262144;

  // stage Q [64][128]: load i covers rows 16i+(t>>4), chunk t&15, src chunk ^= row&7
  {
    const int sc = ((t & 15) ^ ((t >> 4) & 7)) << 3;
    const unsigned short* src = Qg + (size_t)(t >> 4) * 2048 + sc;
    unsigned short* dst = &Qs[t * 8];
#pragma unroll
    for (int i = 0; i < 4; ++i) ld_g2l16(src + (size_t)i * 16 * 2048, dst + i * 2048);
  }
  __syncthreads();
  bf16x8 qf[4];
  {
    const int qr = w * 16 + (lane & 15);
#pragma unroll
    for (int kk = 0; kk < 4; ++kk) {
      const int c = ((kk << 2) + (lane >> 4)) ^ (qr & 7);
      qf[kk] = *(const bf16x8*)&Qs[qr * 128 + c * 8];
    }
  }
  __syncthreads();

  const float SC2 = 0.1275174246f;  // (1/sqrt(128)) * log2(e)
  float m_run[4], l_run[4];
#pragma unroll
  for (int j = 0; j < 4; ++j) { m_run[j] = -1e30f; l_run[j] = 0.f; }
  f32x4 oacc[8] = {};

  // staging addresses (per-thread constants)
  const int ksc = ((t & 15) ^ ((t >> 4) & 7)) << 3;
  const int vsc = ((t & 7) ^ ((t >> 3) & 7)) << 3;
  unsigned short* const Kd = &Ks[t * 8];
  unsigned short* const Vd = &Vs[t * 8];

  for (int kt = 0; kt < 32; ++kt) {
    const unsigned short* ks = Kg + (size_t)(kt * 64 + (t >> 4)) * 1024 + ksc;
    const unsigned short* vs = Vg + (size_t)(t >> 3) * 2048 + kt * 64 + vsc;
#pragma unroll
    for (int i = 0; i < 4; ++i) {
      ld_g2l16(ks + (size_t)i * 16 * 1024, Kd + i * 2048);
      ld_g2l16(vs + (size_t)i * 32 * 2048, Vd + i * 2048);
    }
    __syncthreads();

    // S = Q K^T   (wave's 16 q-rows x 64 kv-cols)
    f32x4 sac[4] = {};
#pragma unroll
    for (int kk = 0; kk < 4; ++kk) {
      bf16x8 kf[4];
#pragma unroll
      for (int n = 0; n < 4; ++n) {
        const int r = n * 16 + (lane & 15);
        const int c = ((kk << 2) + (lane >> 4)) ^ (r & 7);
        kf[n] = *(const bf16x8*)&Ks[r * 128 + c * 8];
      }
#pragma unroll
      for (int n = 0; n < 4; ++n)
        sac[n] = __builtin_amdgcn_mfma_f32_16x16x32_bf16(qf[kk], kf[n], sac[n], 0, 0, 0);
    }

    // online softmax in exp2 domain
#pragma unroll
    for (int n = 0; n < 4; ++n)
#pragma unroll
      for (int j = 0; j < 4; ++j) sac[n][j] *= SC2;
#pragma unroll
    for (int j = 0; j < 4; ++j) {
      float tm = fmaxf(fmaxf(sac[0][j], sac[1][j]), fmaxf(sac[2][j], sac[3][j]));
#pragma unroll
      for (int off = 1; off < 16; off <<= 1) tm = fmaxf(tm, __shfl_xor(tm, off, 64));
      const float mn = fmaxf(m_run[j], tm);
      const float corr = exp2f(m_run[j] - mn);
      m_run[j] = mn;
      float rs = 0.f;
#pragma unroll
      for (int n = 0; n < 4; ++n) {
        const float p = exp2f(sac[n][j] - mn);
        sac[n][j] = p;
        rs += p;
      }
#pragma unroll
      for (int off = 1; off < 16; off <<= 1) rs += __shfl_xor(rs, off, 64);
      l_run[j] = l_run[j] * corr + rs;
#pragma unroll
      for (int di = 0; di < 8; ++di) oacc[di][j] *= corr;
    }

    // write P tile [64][64] bf16 (chunk ^= row&7); wave-private rows
    {
      const int rbase = w * 16 + ((lane >> 4) << 2);
#pragma unroll
      for (int j = 0; j < 4; ++j) {
        const int r = rbase + j;
#pragma unroll
        for (int n = 0; n < 4; ++n) {
          const int col = n * 16 + (lane & 15);
          Ps[r * 64 + (((col >> 3) ^ (r & 7)) << 3) + (lane & 7)] = f2b(sac[n][j]);
        }
      }
    }

    // O += P @ V  (no barrier needed: Ps rows are wave-private)
#pragma unroll
    for (int kk = 0; kk < 2; ++kk) {
      const int pr = w * 16 + (lane & 15);
      const int pc = ((kk << 2) + (lane >> 4)) ^ (pr & 7);
      const bf16x8 pf = *(const bf16x8*)&Ps[pr * 64 + pc * 8];
#pragma unroll
      for (int di = 0; di < 8; ++di) {
        const int r = di * 16 + (lane & 15);
        const int c = ((kk << 2) + (lane >> 4)) ^ (r & 7);
        const bf16x8 vf = *(const bf16x8*)&Vs[r * 64 + c * 8];
        oacc[di] = __builtin_amdgcn_mfma_f32_16x16x32_bf16(pf, vf, oacc[di], 0, 0, 0);
      }
    }
    __syncthreads();
  }

  // epilogue: O /= l, store bf16
  {
    const int rbase = b * 2048 + qt * 64 + w * 16 + ((lane >> 4) << 2);
#pragma unroll
    for (int j = 0; j < 4; ++j) {
      const float inv = 1.0f / l_run[j];
#pragma unroll
      for (int di = 0; di < 8; ++di) {
        const int col = h * 128 + di * 16 + (lane & 15);
        Oa[(size_t)(rbase + j) * 2048 + col] = f2b(oacc[di][j] * inv);
      }
    }
  }
}

// ---------------- launch ----------------

extern "C" void kernel_launch(void* const* d_in, const int* in_sizes, int n_in,
                              void* d_out, int out_size, void* d_ws, size_t ws_size,
                              hipStream_t stream) {
  (void)in_sizes; (void)n_in; (void)out_size; (void)ws_size;
  const float* x  = (const float*)d_in[0];
  const float* wq = (const float*)d_in[1];
  const float* bq = (const float*)d_in[2];
  const float* wk = (const float*)d_in[3];
  const float* bk = (const float*)d_in[4];
  const float* wv = (const float*)d_in[5];
  const float* bv = (const float*)d_in[6];
  const float* wo = (const float*)d_in[7];
  const float* bo = (const float*)d_in[8];

  char* ws = (char*)d_ws;
  unsigned short* xb  = (unsigned short*)(ws);              // [4096][2048] bf16 (reused as attn-out)
  unsigned short* qb  = (unsigned short*)(ws + 16777216);   // [4096][2048]
  unsigned short* kvb = (unsigned short*)(ws + 33554432);   // [4096][1024]  (K | V)
  unsigned short* vT  = (unsigned short*)(ws + 41943040);   // [8][128][2048]
  unsigned short* wqT = (unsigned short*)(ws + 46137344);   // [2048][2048]
  unsigned short* wkT = (unsigned short*)(ws + 54525952);   // [512][2048]  (wvT follows contiguously)
  unsigned short* woT = (unsigned short*)(ws + 58720256);   // [2048][2048]
  unsigned short* wvT = (unsigned short*)(ws + 56623104);   // [512][2048]

  k_cvt<<<4096, 256, 0, stream>>>(x, xb, 4096 * 2048);
  k_tw<<<dim3(64, 64), 256, 0, stream>>>(wq, wqT, 2048, 2048);
  k_tw<<<dim3(16, 64), 256, 0, stream>>>(wk, wkT, 2048, 512);
  k_tw<<<dim3(16, 64), 256, 0, stream>>>(wv, wvT, 2048, 512);
  k_tw<<<dim3(64, 64), 256, 0, stream>>>(wo, woT, 2048, 2048);

  gemm_bt<0><<<dim3(16, 32), 256, 0, stream>>>(xb, wqT, bq, bq, 1 << 30, qb, 4096, 2048, 2048);
  // K and V projections fused: Bt = [wkT ; wvT] (contiguous), N=1024
  gemm_bt<0><<<dim3(8, 32), 256, 0, stream>>>(xb, wkT, bk, bv, 512, kvb, 4096, 1024, 2048);

  k_tv<<<dim3(64, 4, 8), 256, 0, stream>>>(kvb, vT);

  unsigned short* ao = xb;  // reuse x-bf16 buffer for attention output
  flash_gqa<<<dim3(32, 32), 256, 0, stream>>>(qb, kvb, vT, ao);

  gemm_bt<1><<<dim3(16, 32), 256, 0, stream>>>(ao, woT, bo, bo, 1 << 30, (float*)d_out, 4096, 2048, 2048);
}

// Round 4
// 349.228 us; speedup vs baseline: 1.6488x; 1.2193x over previous
//
#include <hip/hip_runtime.h>

typedef short bf16x8 __attribute__((ext_vector_type(8)));
typedef float f32x4 __attribute__((ext_vector_type(4)));
typedef float f32x16 __attribute__((ext_vector_type(16)));
typedef unsigned int u32;

__device__ __forceinline__ unsigned short f2b(float f) {
  union { float f; unsigned int u; } c; c.f = f;
  unsigned int u = c.u + 0x7fffu + ((c.u >> 16) & 1u);
  return (unsigned short)(u >> 16);
}

__device__ __forceinline__ u32 cvtpk(float a, float b) {
  u32 r;
  asm("v_cvt_pk_bf16_f32 %0, %1, %2" : "=v"(r) : "v"(a), "v"(b));
  return r;
}

__device__ __forceinline__ void pswap(u32& a, u32& b) {
  asm("v_permlane32_swap_b32 %0, %1" : "+v"(a), "+v"(b));
}

__device__ __forceinline__ void ld_g2l16(const void* g, void* l) {
  __builtin_amdgcn_global_load_lds(
      (__attribute__((address_space(1))) void*)(void*)g,
      (__attribute__((address_space(3))) void*)l, 16, 0, 0);
}

// ---------------- conversions ----------------

__global__ __launch_bounds__(256) void k_cvt(const float* __restrict__ in,
                                             unsigned short* __restrict__ out, int n) {
  int i = (blockIdx.x * 256 + threadIdx.x) * 4;
  const int stride = gridDim.x * 256 * 4;
  for (; i < n; i += stride) {
    const float4 v = *(const float4*)(in + i);
    unsigned short o0 = f2b(v.x), o1 = f2b(v.y), o2 = f2b(v.z), o3 = f2b(v.w);
    ushort4 o; o.x = o0; o.y = o1; o.z = o2; o.w = o3;
    *(ushort4*)(out + i) = o;
  }
}

// W [K][N] fp32  ->  Wt [N][K] bf16
__global__ __launch_bounds__(256) void k_tw(const float* __restrict__ W,
                                            unsigned short* __restrict__ Wt, int K, int N) {
  __shared__ float tile[32][33];
  const int nb = blockIdx.x * 32, kb = blockIdx.y * 32;
  const int tx = threadIdx.x & 31, ty = threadIdx.x >> 5;
#pragma unroll
  for (int i = 0; i < 32; i += 8)
    tile[ty + i][tx] = W[(size_t)(kb + ty + i) * N + nb + tx];
  __syncthreads();
#pragma unroll
  for (int i = 0; i < 32; i += 8)
    Wt[(size_t)(nb + ty + i) * K + kb + tx] = f2b(tile[tx][ty + i]);
}

// kv [4096][1024] bf16 (v at col 512+) -> vT [8][128][2048] bf16
__global__ __launch_bounds__(256) void k_tv(const unsigned short* __restrict__ v,
                                            unsigned short* __restrict__ vT) {
  __shared__ unsigned short tile[32][33];
  const int sb = blockIdx.x * 32, db = blockIdx.y * 32;
  const int ob = blockIdx.z, b = ob >> 2, kvh = ob & 3;
  const int tx = threadIdx.x & 31, ty = threadIdx.x >> 5;
#pragma unroll
  for (int i = 0; i < 32; i += 8)
    tile[ty + i][tx] = v[(size_t)(b * 2048 + sb + ty + i) * 1024 + 512 + kvh * 128 + db + tx];
  __syncthreads();
#pragma unroll
  for (int i = 0; i < 32; i += 8)
    vT[(size_t)ob * 262144 + (size_t)(db + ty + i) * 2048 + sb + tx] = tile[tx][ty + i];
}

// ---------------- GEMM: C[M][N] = A[M][K] @ Bt[N][K]^T + bias ----------------

template <int OUT_F32>
__global__ __launch_bounds__(256) void gemm_bt(const unsigned short* __restrict__ A,
                                               const unsigned short* __restrict__ Bt,
                                               const float* __restrict__ bias,
                                               const float* __restrict__ bias2,
                                               int nsplit,
                                               void* __restrict__ Cout,
                                               int M, int N, int K) {
  __shared__ unsigned short As[8192] __attribute__((aligned(16)));
  __shared__ unsigned short Bs[8192] __attribute__((aligned(16)));
  const int t = threadIdx.x, w = t >> 6, lane = t & 63;
  const int wr = w >> 1, wc = w & 1;
  const int bm = blockIdx.y, bn = blockIdx.x;

  f32x4 acc[4][4] = {};

  const int srow = w * 8 + (lane >> 3);
  const int scol = ((lane & 7) ^ (lane >> 3)) << 3;
  const unsigned short* Ap = A + (size_t)(bm * 128 + srow) * K + scol;
  const unsigned short* Bp = Bt + (size_t)(bn * 128 + srow) * K + scol;
  unsigned short* Ad = &As[(w * 64 + lane) * 8];
  unsigned short* Bd = &Bs[(w * 64 + lane) * 8];

  const int nkt = K >> 6;
  for (int kt = 0; kt < nkt; ++kt) {
#pragma unroll
    for (int i = 0; i < 4; ++i) {
      ld_g2l16(Ap + (size_t)i * 32 * K, Ad + i * 2048);
      ld_g2l16(Bp + (size_t)i * 32 * K, Bd + i * 2048);
    }
    Ap += 64; Bp += 64;
    __syncthreads();
#pragma unroll
    for (int kk = 0; kk < 2; ++kk) {
      bf16x8 av[4], bv[4];
#pragma unroll
      for (int m = 0; m < 4; ++m) {
        int r = wr * 64 + m * 16 + (lane & 15);
        int c = ((kk << 2) + (lane >> 4)) ^ (r & 7);
        av[m] = *(const bf16x8*)&As[r * 64 + c * 8];
      }
#pragma unroll
      for (int n = 0; n < 4; ++n) {
        int r = wc * 64 + n * 16 + (lane & 15);
        int c = ((kk << 2) + (lane >> 4)) ^ (r & 7);
        bv[n] = *(const bf16x8*)&Bs[r * 64 + c * 8];
      }
#pragma unroll
      for (int m = 0; m < 4; ++m)
#pragma unroll
        for (int n = 0; n < 4; ++n)
          acc[m][n] = __builtin_amdgcn_mfma_f32_16x16x32_bf16(av[m], bv[n], acc[m][n], 0, 0, 0);
    }
    __syncthreads();
  }

  const int row0 = bm * 128 + wr * 64 + ((lane >> 4) << 2);
  const int col0 = bn * 128 + wc * 64 + (lane & 15);
#pragma unroll
  for (int n = 0; n < 4; ++n) {
    const int c = col0 + n * 16;
    const float bb = (c < nsplit) ? bias[c] : bias2[c - nsplit];
#pragma unroll
    for (int m = 0; m < 4; ++m) {
#pragma unroll
      for (int j = 0; j < 4; ++j) {
        const float v = acc[m][n][j] + bb;
        const size_t idx = (size_t)(row0 + m * 16 + j) * N + c;
        if (OUT_F32) ((float*)Cout)[idx] = v;
        else ((unsigned short*)Cout)[idx] = f2b(v);
      }
    }
  }
}

// ---------------- flash attention (GQA), 32x32 swapped-operand ----------------
// grid (16 q-tiles of 128 rows, 32 b*h). Block: 4 waves, each owns 32 q-rows.
// KVBLK=64, double-buffered K[64][128]/V^T[128][64] in 64KB LDS, XOR-swizzled.
// S^T = mfma(K,Q): lane owns q = lane&31 -> in-lane softmax.
// P^T B-frags built in-register via v_cvt_pk_bf16_f32 + v_permlane32_swap.
// O^T accumulated; transposed through LDS at epilogue for coalesced store.

__global__ __launch_bounds__(256, 2) void flash_gqa(const unsigned short* __restrict__ Q,
                                                    const unsigned short* __restrict__ Kx,
                                                    const unsigned short* __restrict__ Vt,
                                                    unsigned short* __restrict__ Oa) {
  __shared__ unsigned short smem[32768] __attribute__((aligned(16)));
  const int t = threadIdx.x, w = t >> 6, lane = t & 63;
  const int lo = lane & 31, hi1 = lane >> 5;
  const int qt = blockIdx.x, bh = blockIdx.y;
  const int b = bh >> 4, h = bh & 15, kvh = h >> 2;

  const unsigned short* Qg = Q + (size_t)(b * 2048 + qt * 128) * 2048 + h * 128;
  const unsigned short* Kg = Kx + (size_t)(b * 2048) * 1024 + kvh * 128;
  const unsigned short* Vg = Vt + (size_t)(b * 4 + kvh) * 262144;

  // ---- stage Q [128][128] (chunk ^= row&7), hoist fragments
  {
    const int sc = ((t & 15) ^ ((t >> 4) & 7)) << 3;
    const unsigned short* src = Qg + (size_t)(t >> 4) * 2048 + sc;
    unsigned short* dst = &smem[t * 8];
#pragma unroll
    for (int i = 0; i < 8; ++i) ld_g2l16(src + (size_t)i * 16 * 2048, dst + i * 2048);
  }
  __syncthreads();
  bf16x8 qf[8];
  {
    const int r = w * 32 + lo;
#pragma unroll
    for (int kk = 0; kk < 8; ++kk) {
      const int c8 = (2 * kk + hi1) ^ (r & 7);
      qf[kk] = *(const bf16x8*)&smem[r * 128 + c8 * 8];
    }
  }
  __syncthreads();

  unsigned short* const K0 = smem;
  unsigned short* const V0 = smem + 8192;
  unsigned short* const K1 = smem + 16384;
  unsigned short* const V1 = smem + 24576;

  const int kchunk_src = ((t & 15) ^ ((t >> 4) & 7)) << 3;
  const int vchunk_src = ((t & 7) ^ ((t >> 3) & 7)) << 3;

  auto stage = [&](int kt, unsigned short* Kd, unsigned short* Vd) {
    const unsigned short* ks = Kg + (size_t)(kt * 64 + (t >> 4)) * 1024 + kchunk_src;
    const unsigned short* vs = Vg + (size_t)(t >> 3) * 2048 + kt * 64 + vchunk_src;
#pragma unroll
    for (int i = 0; i < 4; ++i) {
      ld_g2l16(ks + (size_t)i * 16384, Kd + t * 8 + i * 2048);
      ld_g2l16(vs + (size_t)i * 65536, Vd + t * 8 + i * 2048);
    }
  };

  const float SC2 = 0.1275174246f;  // (1/sqrt(128)) * log2(e)
  float m_run = -1e30f, l_run = 0.f;
  f32x16 oT[4] = {};

  stage(0, K0, V0);
  __syncthreads();

  for (int kt = 0; kt < 32; ++kt) {
    unsigned short* const Kc = (kt & 1) ? K1 : K0;
    unsigned short* const Vc = (kt & 1) ? V1 : V0;
    if (kt < 31) stage(kt + 1, (kt & 1) ? K0 : K1, (kt & 1) ? V0 : V1);

    // S^T = K Q^T : two 32-kv tiles, lane owns column q = lo
    f32x16 sa0 = {}, sa1 = {};
    __builtin_amdgcn_s_setprio(1);
#pragma unroll
    for (int kk = 0; kk < 8; ++kk) {
      const int c8 = (2 * kk + hi1) ^ (lo & 7);
      const bf16x8 kf0 = *(const bf16x8*)&Kc[lo * 128 + c8 * 8];
      const bf16x8 kf1 = *(const bf16x8*)&Kc[(32 + lo) * 128 + c8 * 8];
      sa0 = __builtin_amdgcn_mfma_f32_32x32x16_bf16(kf0, qf[kk], sa0, 0, 0, 0);
      sa1 = __builtin_amdgcn_mfma_f32_32x32x16_bf16(kf1, qf[kk], sa1, 0, 0, 0);
    }
    __builtin_amdgcn_s_setprio(0);

    // in-lane max over 32 kv (tree), then one cross-half swap
    float tmax[8];
#pragma unroll
    for (int i = 0; i < 8; ++i) tmax[i] = fmaxf(sa0[i], sa0[i + 8]);
#pragma unroll
    for (int i = 0; i < 8; ++i) tmax[i] = fmaxf(tmax[i], fmaxf(sa1[i], sa1[i + 8]));
    float tm = fmaxf(fmaxf(fmaxf(tmax[0], tmax[1]), fmaxf(tmax[2], tmax[3])),
                     fmaxf(fmaxf(tmax[4], tmax[5]), fmaxf(tmax[6], tmax[7])));
    tm *= SC2;
    tm = fmaxf(tm, __shfl_xor(tm, 32, 64));

    // defer-max (T13): rescale only when max grew past threshold
    if (!__all(tm <= m_run + 8.f)) {
      const float mn = fmaxf(m_run, tm);
      const float corr = exp2f(m_run - mn);
      m_run = mn;
      l_run *= corr;
#pragma unroll
      for (int d = 0; d < 4; ++d)
#pragma unroll
        for (int i = 0; i < 16; ++i) oT[d][i] *= corr;
    }

    float r0 = 0.f, r1 = 0.f, r2 = 0.f, r3 = 0.f;
#pragma unroll
    for (int i = 0; i < 4; ++i) {
      float p0 = exp2f(fmaf(sa0[i], SC2, -m_run));      sa0[i] = p0;      r0 += p0;
      float p1 = exp2f(fmaf(sa0[i + 4], SC2, -m_run));  sa0[i + 4] = p1;  r1 += p1;
      float p2 = exp2f(fmaf(sa0[i + 8], SC2, -m_run));  sa0[i + 8] = p2;  r2 += p2;
      float p3 = exp2f(fmaf(sa0[i + 12], SC2, -m_run)); sa0[i + 12] = p3; r3 += p3;
    }
#pragma unroll
    for (int i = 0; i < 4; ++i) {
      float p0 = exp2f(fmaf(sa1[i], SC2, -m_run));      sa1[i] = p0;      r0 += p0;
      float p1 = exp2f(fmaf(sa1[i + 4], SC2, -m_run));  sa1[i + 4] = p1;  r1 += p1;
      float p2 = exp2f(fmaf(sa1[i + 8], SC2, -m_run));  sa1[i + 8] = p2;  r2 += p2;
      float p3 = exp2f(fmaf(sa1[i + 12], SC2, -m_run)); sa1[i + 12] = p3; r3 += p3;
    }
    float rs = (r0 + r1) + (r2 + r3);
    rs += __shfl_xor(rs, 32, 64);
    l_run += rs;

    // pack P^T into PV B-frags: cvt_pk pairs + permlane32_swap (T12)
    bf16x8 pf[4];
#pragma unroll
    for (int m = 0; m < 4; ++m) {
      const int base = (m & 1) * 8;
      u32 alo, ahi, blo, bhi;
      if (m < 2) {
        alo = cvtpk(sa0[base + 0], sa0[base + 1]);
        ahi = cvtpk(sa0[base + 2], sa0[base + 3]);
        blo = cvtpk(sa0[base + 4], sa0[base + 5]);
        bhi = cvtpk(sa0[base + 6], sa0[base + 7]);
      } else {
        alo = cvtpk(sa1[base + 0], sa1[base + 1]);
        ahi = cvtpk(sa1[base + 2], sa1[base + 3]);
        blo = cvtpk(sa1[base + 4], sa1[base + 5]);
        bhi = cvtpk(sa1[base + 6], sa1[base + 7]);
      }
      pswap(alo, blo);
      pswap(ahi, bhi);
      union { u32 u[4]; bf16x8 v; } pk;
      pk.u[0] = alo; pk.u[1] = ahi; pk.u[2] = blo; pk.u[3] = bhi;
      pf[m] = pk.v;
    }

    // O^T += V^T P^T
    __builtin_amdgcn_s_setprio(1);
#pragma unroll
    for (int m = 0; m < 4; ++m) {
#pragma unroll
      for (int d = 0; d < 4; ++d) {
        const int r = d * 32 + lo;
        const int c = (2 * m + hi1) ^ (lo & 7);
        const bf16x8 vf = *(const bf16x8*)&Vc[r * 64 + c * 8];
        oT[d] = __builtin_amdgcn_mfma_f32_32x32x16_bf16(vf, pf[m], oT[d], 0, 0, 0);
      }
    }
    __builtin_amdgcn_s_setprio(0);
    __syncthreads();
  }

  // ---- epilogue: O^T/l -> LDS transpose -> coalesced bf16 store
  const float inv = 1.0f / l_run;
  u32* const Ot = (u32*)smem;  // [128 q][64 dwords]
  {
    const int row = w * 32 + lo;
#pragma unroll
    for (int d = 0; d < 4; ++d) {
#pragma unroll
      for (int j2 = 0; j2 < 4; ++j2) {
#pragma unroll
        for (int p = 0; p < 2; ++p) {
          const int rg = 4 * j2 + 2 * p;
          const u32 pk = cvtpk(oT[d][rg] * inv, oT[d][rg + 1] * inv);
          const int dw = d * 16 + 4 * j2 + 2 * hi1 + p;
          Ot[row * 64 + (((dw >> 2) ^ (row & 15)) << 2) + (dw & 3)] = pk;
        }
      }
    }
  }
  __syncthreads();
  {
#pragma unroll
    for (int i = 0; i < 8; ++i) {
      const int row = i * 16 + (t >> 4);
      const int c4 = (t & 15) ^ (row & 15);
      const int4 val = *(const int4*)&Ot[row * 64 + c4 * 4];
      *(int4*)&Oa[(size_t)(b * 2048 + qt * 128 + row) * 2048 + h * 128 + (t & 15) * 8] = val;
    }
  }
}

// ---------------- launch ----------------

extern "C" void kernel_launch(void* const* d_in, const int* in_sizes, int n_in,
                              void* d_out, int out_size, void* d_ws, size_t ws_size,
                              hipStream_t stream) {
  (void)in_sizes; (void)n_in; (void)out_size; (void)ws_size;
  const float* x  = (const float*)d_in[0];
  const float* wq = (const float*)d_in[1];
  const float* bq = (const float*)d_in[2];
  const float* wk = (const float*)d_in[3];
  const float* bk = (const float*)d_in[4];
  const float* wv = (const float*)d_in[5];
  const float* bv = (const float*)d_in[6];
  const float* wo = (const float*)d_in[7];
  const float* bo = (const float*)d_in[8];

  char* ws = (char*)d_ws;
  unsigned short* xb  = (unsigned short*)(ws);              // [4096][2048] bf16 (reused as attn-out)
  unsigned short* qb  = (unsigned short*)(ws + 16777216);   // [4096][2048]
  unsigned short* kvb = (unsigned short*)(ws + 33554432);   // [4096][1024]  (K | V)
  unsigned short* vT  = (unsigned short*)(ws + 41943040);   // [8][128][2048]
  unsigned short* wqT = (unsigned short*)(ws + 46137344);   // [2048][2048]
  unsigned short* wkT = (unsigned short*)(ws + 54525952);   // [512][2048]  (wvT follows contiguously)
  unsigned short* wvT = (unsigned short*)(ws + 56623104);   // [512][2048]
  unsigned short* woT = (unsigned short*)(ws + 58720256);   // [2048][2048]

  k_cvt<<<4096, 256, 0, stream>>>(x, xb, 4096 * 2048);
  k_tw<<<dim3(64, 64), 256, 0, stream>>>(wq, wqT, 2048, 2048);
  k_tw<<<dim3(16, 64), 256, 0, stream>>>(wk, wkT, 2048, 512);
  k_tw<<<dim3(16, 64), 256, 0, stream>>>(wv, wvT, 2048, 512);
  k_tw<<<dim3(64, 64), 256, 0, stream>>>(wo, woT, 2048, 2048);

  gemm_bt<0><<<dim3(16, 32), 256, 0, stream>>>(xb, wqT, bq, bq, 1 << 30, qb, 4096, 2048, 2048);
  // K and V projections fused: Bt = [wkT ; wvT] (contiguous), N=1024
  gemm_bt<0><<<dim3(8, 32), 256, 0, stream>>>(xb, wkT, bk, bv, 512, kvb, 4096, 1024, 2048);

  k_tv<<<dim3(64, 4, 8), 256, 0, stream>>>(kvb, vT);

  unsigned short* ao = xb;  // reuse x-bf16 buffer for attention output
  flash_gqa<<<dim3(16, 32), 256, 0, stream>>>(qb, kvb, vT, ao);

  gemm_bt<1><<<dim3(16, 32), 256, 0, stream>>>(ao, woT, bo, bo, 1 << 30, (float*)d_out, 4096, 2048, 2048);
}

// Round 11
// 345.319 us; speedup vs baseline: 1.6675x; 1.0113x over previous
//
#include <hip/hip_runtime.h>

typedef short bf16x8 __attribute__((ext_vector_type(8)));
typedef float f32x4 __attribute__((ext_vector_type(4)));
typedef float f32x16 __attribute__((ext_vector_type(16)));
typedef unsigned int u32;

__device__ __forceinline__ unsigned short f2b(float f) {
  union { float f; unsigned int u; } c; c.f = f;
  unsigned int u = c.u + 0x7fffu + ((c.u >> 16) & 1u);
  return (unsigned short)(u >> 16);
}

__device__ __forceinline__ u32 cvtpk(float a, float b) {
  u32 r;
  asm("v_cvt_pk_bf16_f32 %0, %1, %2" : "=v"(r) : "v"(a), "v"(b));
  return r;
}

__device__ __forceinline__ void pswap(u32& a, u32& b) {
  asm("v_permlane32_swap_b32 %0, %1" : "+v"(a), "+v"(b));
}

__device__ __forceinline__ void ld_g2l16(const void* g, void* l) {
  __builtin_amdgcn_global_load_lds(
      (__attribute__((address_space(1))) void*)(void*)g,
      (__attribute__((address_space(3))) void*)l, 16, 0, 0);
}

// ---------------- conversions ----------------

__global__ __launch_bounds__(256) void k_cvt(const float* __restrict__ in,
                                             unsigned short* __restrict__ out, int n) {
  int i = (blockIdx.x * 256 + threadIdx.x) * 4;
  const int stride = gridDim.x * 256 * 4;
  for (; i < n; i += stride) {
    const float4 v = *(const float4*)(in + i);
    unsigned short o0 = f2b(v.x), o1 = f2b(v.y), o2 = f2b(v.z), o3 = f2b(v.w);
    ushort4 o; o.x = o0; o.y = o1; o.z = o2; o.w = o3;
    *(ushort4*)(out + i) = o;
  }
}

// W [K][N] fp32  ->  Wt [N][K] bf16
__global__ __launch_bounds__(256) void k_tw(const float* __restrict__ W,
                                            unsigned short* __restrict__ Wt, int K, int N) {
  __shared__ float tile[32][33];
  const int nb = blockIdx.x * 32, kb = blockIdx.y * 32;
  const int tx = threadIdx.x & 31, ty = threadIdx.x >> 5;
#pragma unroll
  for (int i = 0; i < 32; i += 8)
    tile[ty + i][tx] = W[(size_t)(kb + ty + i) * N + nb + tx];
  __syncthreads();
#pragma unroll
  for (int i = 0; i < 32; i += 8)
    Wt[(size_t)(nb + ty + i) * K + kb + tx] = f2b(tile[tx][ty + i]);
}

// qkv [4096][3072] bf16 (v at col 2560+) -> vT [8][128][2048] bf16
__global__ __launch_bounds__(256) void k_tv(const unsigned short* __restrict__ v,
                                            unsigned short* __restrict__ vT) {
  __shared__ unsigned short tile[32][33];
  const int sb = blockIdx.x * 32, db = blockIdx.y * 32;
  const int ob = blockIdx.z, b = ob >> 2, kvh = ob & 3;
  const int tx = threadIdx.x & 31, ty = threadIdx.x >> 5;
#pragma unroll
  for (int i = 0; i < 32; i += 8)
    tile[ty + i][tx] = v[(size_t)(b * 2048 + sb + ty + i) * 3072 + 2560 + kvh * 128 + db + tx];
  __syncthreads();
#pragma unroll
  for (int i = 0; i < 32; i += 8)
    vT[(size_t)ob * 262144 + (size_t)(db + ty + i) * 2048 + sb + tx] = tile[tx][ty + i];
}

// ---------------- GEMM: C[M][N] = A[M][K] @ Bt[N][K]^T + bias ----------------
// 128x128 tile, BK=64, 4 waves, global_load_lds staging with pre-swizzled
// source (chunk ^= row&7). 3-way bias select at col splits s1/s2.

template <int OUT_F32>
__global__ __launch_bounds__(256) void gemm_bt(const unsigned short* __restrict__ A,
                                               const unsigned short* __restrict__ Bt,
                                               const float* __restrict__ bias0,
                                               const float* __restrict__ bias1,
                                               const float* __restrict__ bias2,
                                               int s1, int s2,
                                               void* __restrict__ Cout,
                                               int M, int N, int K) {
  __shared__ unsigned short As[8192] __attribute__((aligned(16)));
  __shared__ unsigned short Bs[8192] __attribute__((aligned(16)));
  const int t = threadIdx.x, w = t >> 6, lane = t & 63;
  const int wr = w >> 1, wc = w & 1;
  const int bm = blockIdx.y, bn = blockIdx.x;

  f32x4 acc[4][4] = {};

  const int srow = w * 8 + (lane >> 3);
  const int scol = ((lane & 7) ^ (lane >> 3)) << 3;
  const unsigned short* Ap = A + (size_t)(bm * 128 + srow) * K + scol;
  const unsigned short* Bp = Bt + (size_t)(bn * 128 + srow) * K + scol;
  unsigned short* Ad = &As[(w * 64 + lane) * 8];
  unsigned short* Bd = &Bs[(w * 64 + lane) * 8];

  const int nkt = K >> 6;
  for (int kt = 0; kt < nkt; ++kt) {
#pragma unroll
    for (int i = 0; i < 4; ++i) {
      ld_g2l16(Ap + (size_t)i * 32 * K, Ad + i * 2048);
      ld_g2l16(Bp + (size_t)i * 32 * K, Bd + i * 2048);
    }
    Ap += 64; Bp += 64;
    __syncthreads();
#pragma unroll
    for (int kk = 0; kk < 2; ++kk) {
      bf16x8 av[4], bv[4];
#pragma unroll
      for (int m = 0; m < 4; ++m) {
        int r = wr * 64 + m * 16 + (lane & 15);
        int c = ((kk << 2) + (lane >> 4)) ^ (r & 7);
        av[m] = *(const bf16x8*)&As[r * 64 + c * 8];
      }
#pragma unroll
      for (int n = 0; n < 4; ++n) {
        int r = wc * 64 + n * 16 + (lane & 15);
        int c = ((kk << 2) + (lane >> 4)) ^ (r & 7);
        bv[n] = *(const bf16x8*)&Bs[r * 64 + c * 8];
      }
#pragma unroll
      for (int m = 0; m < 4; ++m)
#pragma unroll
        for (int n = 0; n < 4; ++n)
          acc[m][n] = __builtin_amdgcn_mfma_f32_16x16x32_bf16(av[m], bv[n], acc[m][n], 0, 0, 0);
    }
    __syncthreads();
  }

  const int row0 = bm * 128 + wr * 64 + ((lane >> 4) << 2);
  const int col0 = bn * 128 + wc * 64 + (lane & 15);
#pragma unroll
  for (int n = 0; n < 4; ++n) {
    const int c = col0 + n * 16;
    const float bb = (c < s1) ? bias0[c] : ((c < s2) ? bias1[c - s1] : bias2[c - s2]);
#pragma unroll
    for (int m = 0; m < 4; ++m) {
#pragma unroll
      for (int j = 0; j < 4; ++j) {
        const float v = acc[m][n][j] + bb;
        const size_t idx = (size_t)(row0 + m * 16 + j) * N + c;
        if (OUT_F32) ((float*)Cout)[idx] = v;
        else ((unsigned short*)Cout)[idx] = f2b(v);
      }
    }
  }
}

// ---------------- flash attention (GQA), 32x32 swapped-operand ----------------
// grid (16 q-tiles of 128 rows, 32 b*h). Block: 4 waves, each owns 32 q-rows.
// QKV packed [4096][3072]: Q cols 0..2047, K cols 2048..2559 (kvh*128 slice).
// KVBLK=64, double-buffered K[64][128]/V^T[128][64] in 64KB LDS, XOR-swizzled.
// S^T = mfma(K,Q): lane owns q = lane&31 -> in-lane softmax.
// exp2f (OCML = single v_exp_f32, hazard-safe) + __shfl_xor cross-half reduce:
// the raw-asm v_exp_f32 variant hit the CDNA trans-op read hazard (r8 FAIL).
// P^T B-frags built in-register via v_cvt_pk_bf16_f32 + v_permlane32_swap.

__global__ __launch_bounds__(256, 2) void flash_gqa(const unsigned short* __restrict__ QKV,
                                                    const unsigned short* __restrict__ Vt,
                                                    unsigned short* __restrict__ Oa) {
  __shared__ unsigned short smem[32768] __attribute__((aligned(16)));
  const int t = threadIdx.x, w = t >> 6, lane = t & 63;
  const int lo = lane & 31, hi1 = lane >> 5;
  const int qt = blockIdx.x, bh = blockIdx.y;
  const int b = bh >> 4, h = bh & 15, kvh = h >> 2;

  const unsigned short* Qg = QKV + (size_t)(b * 2048 + qt * 128) * 3072 + h * 128;
  const unsigned short* Kg = QKV + (size_t)(b * 2048) * 3072 + 2048 + kvh * 128;
  const unsigned short* Vg = Vt + (size_t)(b * 4 + kvh) * 262144;

  // ---- stage Q [128][128] (chunk ^= row&7), hoist fragments
  {
    const int sc = ((t & 15) ^ ((t >> 4) & 7)) << 3;
    const unsigned short* src = Qg + (size_t)(t >> 4) * 3072 + sc;
    unsigned short* dst = &smem[t * 8];
#pragma unroll
    for (int i = 0; i < 8; ++i) ld_g2l16(src + (size_t)i * 16 * 3072, dst + i * 2048);
  }
  __syncthreads();
  bf16x8 qf[8];
  {
    const int r = w * 32 + lo;
#pragma unroll
    for (int kk = 0; kk < 8; ++kk) {
      const int c8 = (2 * kk + hi1) ^ (r & 7);
      qf[kk] = *(const bf16x8*)&smem[r * 128 + c8 * 8];
    }
  }
  __syncthreads();

  unsigned short* const K0 = smem;
  unsigned short* const V0 = smem + 8192;
  unsigned short* const K1 = smem + 16384;
  unsigned short* const V1 = smem + 24576;

  const int kchunk_src = ((t & 15) ^ ((t >> 4) & 7)) << 3;
  const int vchunk_src = ((t & 7) ^ ((t >> 3) & 7)) << 3;

  auto stage = [&](int kt, unsigned short* Kd, unsigned short* Vd) {
    const unsigned short* ks = Kg + (size_t)(kt * 64 + (t >> 4)) * 3072 + kchunk_src;
    const unsigned short* vs = Vg + (size_t)(t >> 3) * 2048 + kt * 64 + vchunk_src;
#pragma unroll
    for (int i = 0; i < 4; ++i) {
      ld_g2l16(ks + (size_t)i * 16 * 3072, Kd + t * 8 + i * 2048);
      ld_g2l16(vs + (size_t)i * 65536, Vd + t * 8 + i * 2048);
    }
  };

  const float SC2 = 0.1275174246f;  // (1/sqrt(128)) * log2(e)
  float m_run = -1e30f, l_run = 0.f;
  f32x16 oT[4] = {};

  stage(0, K0, V0);
  __syncthreads();

  for (int kt = 0; kt < 32; ++kt) {
    unsigned short* const Kc = (kt & 1) ? K1 : K0;
    unsigned short* const Vc = (kt & 1) ? V1 : V0;
    if (kt < 31) stage(kt + 1, (kt & 1) ? K0 : K1, (kt & 1) ? V0 : V1);

    // S^T = K Q^T : two 32-kv tiles, lane owns column q = lo
    f32x16 sa0 = {}, sa1 = {};
    __builtin_amdgcn_s_setprio(1);
#pragma unroll
    for (int kk = 0; kk < 8; ++kk) {
      const int c8 = (2 * kk + hi1) ^ (lo & 7);
      const bf16x8 kf0 = *(const bf16x8*)&Kc[lo * 128 + c8 * 8];
      const bf16x8 kf1 = *(const bf16x8*)&Kc[(32 + lo) * 128 + c8 * 8];
      sa0 = __builtin_amdgcn_mfma_f32_32x32x16_bf16(kf0, qf[kk], sa0, 0, 0, 0);
      sa1 = __builtin_amdgcn_mfma_f32_32x32x16_bf16(kf1, qf[kk], sa1, 0, 0, 0);
    }
    __builtin_amdgcn_s_setprio(0);

    // in-lane max over 32 kv (tree), then one cross-half swap
    float tmax[8];
#pragma unroll
    for (int i = 0; i < 8; ++i) tmax[i] = fmaxf(sa0[i], sa0[i + 8]);
#pragma unroll
    for (int i = 0; i < 8; ++i) tmax[i] = fmaxf(tmax[i], fmaxf(sa1[i], sa1[i + 8]));
    float tm = fmaxf(fmaxf(fmaxf(tmax[0], tmax[1]), fmaxf(tmax[2], tmax[3])),
                     fmaxf(fmaxf(tmax[4], tmax[5]), fmaxf(tmax[6], tmax[7])));
    tm *= SC2;
    tm = fmaxf(tm, __shfl_xor(tm, 32, 64));

    // defer-max (T13): rescale only when max grew past threshold
    if (!__all(tm <= m_run + 8.f)) {
      const float mn = fmaxf(m_run, tm);
      const float corr = exp2f(m_run - mn);
      m_run = mn;
      l_run *= corr;
#pragma unroll
      for (int d = 0; d < 4; ++d)
#pragma unroll
        for (int i = 0; i < 16; ++i) oT[d][i] *= corr;
    }

    float r0 = 0.f, r1 = 0.f, r2 = 0.f, r3 = 0.f;
#pragma unroll
    for (int i = 0; i < 4; ++i) {
      float p0 = exp2f(fmaf(sa0[i], SC2, -m_run));      sa0[i] = p0;      r0 += p0;
      float p1 = exp2f(fmaf(sa0[i + 4], SC2, -m_run));  sa0[i + 4] = p1;  r1 += p1;
      float p2 = exp2f(fmaf(sa0[i + 8], SC2, -m_run));  sa0[i + 8] = p2;  r2 += p2;
      float p3 = exp2f(fmaf(sa0[i + 12], SC2, -m_run)); sa0[i + 12] = p3; r3 += p3;
    }
#pragma unroll
    for (int i = 0; i < 4; ++i) {
      float p0 = exp2f(fmaf(sa1[i], SC2, -m_run));      sa1[i] = p0;      r0 += p0;
      float p1 = exp2f(fmaf(sa1[i + 4], SC2, -m_run));  sa1[i + 4] = p1;  r1 += p1;
      float p2 = exp2f(fmaf(sa1[i + 8], SC2, -m_run));  sa1[i + 8] = p2;  r2 += p2;
      float p3 = exp2f(fmaf(sa1[i + 12], SC2, -m_run)); sa1[i + 12] = p3; r3 += p3;
    }
    float rs = (r0 + r1) + (r2 + r3);
    rs += __shfl_xor(rs, 32, 64);
    l_run += rs;

    // pack P^T into PV B-frags: cvt_pk pairs + permlane32_swap (T12)
    bf16x8 pf[4];
#pragma unroll
    for (int m = 0; m < 4; ++m) {
      const int base = (m & 1) * 8;
      u32 alo, ahi, blo, bhi;
      if (m < 2) {
        alo = cvtpk(sa0[base + 0], sa0[base + 1]);
        ahi = cvtpk(sa0[base + 2], sa0[base + 3]);
        blo = cvtpk(sa0[base + 4], sa0[base + 5]);
        bhi = cvtpk(sa0[base + 6], sa0[base + 7]);
      } else {
        alo = cvtpk(sa1[base + 0], sa1[base + 1]);
        ahi = cvtpk(sa1[base + 2], sa1[base + 3]);
        blo = cvtpk(sa1[base + 4], sa1[base + 5]);
        bhi = cvtpk(sa1[base + 6], sa1[base + 7]);
      }
      pswap(alo, blo);
      pswap(ahi, bhi);
      union { u32 u[4]; bf16x8 v; } pk;
      pk.u[0] = alo; pk.u[1] = ahi; pk.u[2] = blo; pk.u[3] = bhi;
      pf[m] = pk.v;
    }

    // O^T += V^T P^T
    __builtin_amdgcn_s_setprio(1);
#pragma unroll
    for (int m = 0; m < 4; ++m) {
#pragma unroll
      for (int d = 0; d < 4; ++d) {
        const int r = d * 32 + lo;
        const int c = (2 * m + hi1) ^ (lo & 7);
        const bf16x8 vf = *(const bf16x8*)&Vc[r * 64 + c * 8];
        oT[d] = __builtin_amdgcn_mfma_f32_32x32x16_bf16(vf, pf[m], oT[d], 0, 0, 0);
      }
    }
    __builtin_amdgcn_s_setprio(0);
    __syncthreads();
  }

  // ---- epilogue: O^T/l -> LDS transpose -> coalesced bf16 store
  const float inv = 1.0f / l_run;
  u32* const Ot = (u32*)smem;  // [128 q][64 dwords]
  {
    const int row = w * 32 + lo;
#pragma unroll
    for (int d = 0; d < 4; ++d) {
#pragma unroll
      for (int j2 = 0; j2 < 4; ++j2) {
#pragma unroll
        for (int p = 0; p < 2; ++p) {
          const int rg = 4 * j2 + 2 * p;
          const u32 pk = cvtpk(oT[d][rg] * inv, oT[d][rg + 1] * inv);
          const int dw = d * 16 + 4 * j2 + 2 * hi1 + p;
          Ot[row * 64 + (((dw >> 2) ^ (row & 15)) << 2) + (dw & 3)] = pk;
        }
      }
    }
  }
  __syncthreads();
  {
#pragma unroll
    for (int i = 0; i < 8; ++i) {
      const int row = i * 16 + (t >> 4);
      const int c4 = (t & 15) ^ (row & 15);
      const int4 val = *(const int4*)&Ot[row * 64 + c4 * 4];
      *(int4*)&Oa[(size_t)(b * 2048 + qt * 128 + row) * 2048 + h * 128 + (t & 15) * 8] = val;
    }
  }
}

// ---------------- launch ----------------

extern "C" void kernel_launch(void* const* d_in, const int* in_sizes, int n_in,
                              void* d_out, int out_size, void* d_ws, size_t ws_size,
                              hipStream_t stream) {
  (void)in_sizes; (void)n_in; (void)out_size; (void)ws_size;
  const float* x  = (const float*)d_in[0];
  const float* wq = (const float*)d_in[1];
  const float* bq = (const float*)d_in[2];
  const float* wk = (const float*)d_in[3];
  const float* bk = (const float*)d_in[4];
  const float* wv = (const float*)d_in[5];
  const float* bv = (const float*)d_in[6];
  const float* wo = (const float*)d_in[7];
  const float* bo = (const float*)d_in[8];

  char* ws = (char*)d_ws;
  unsigned short* xb    = (unsigned short*)(ws);              // [4096][2048] bf16 (reused as attn-out)
  unsigned short* qkvb  = (unsigned short*)(ws + 16777216);   // [4096][3072] bf16 (Q|K|V)
  unsigned short* vT    = (unsigned short*)(ws + 41943040);   // [8][128][2048]
  unsigned short* wqkvT = (unsigned short*)(ws + 46137344);   // [3072][2048] (wqT|wkT|wvT)
  unsigned short* woT   = (unsigned short*)(ws + 58720256);   // [2048][2048]

  k_cvt<<<4096, 256, 0, stream>>>(x, xb, 4096 * 2048);
  k_tw<<<dim3(64, 64), 256, 0, stream>>>(wq, wqkvT, 2048, 2048);
  k_tw<<<dim3(16, 64), 256, 0, stream>>>(wk, wqkvT + (size_t)2048 * 2048, 2048, 512);
  k_tw<<<dim3(16, 64), 256, 0, stream>>>(wv, wqkvT + (size_t)2560 * 2048, 2048, 512);
  k_tw<<<dim3(64, 64), 256, 0, stream>>>(wo, woT, 2048, 2048);

  // fused Q|K|V projection: N = 3072
  gemm_bt<0><<<dim3(24, 32), 256, 0, stream>>>(xb, wqkvT, bq, bk, bv, 2048, 2560,
                                               qkvb, 4096, 3072, 2048);

  k_tv<<<dim3(64, 4, 8), 256, 0, stream>>>(qkvb, vT);

  unsigned short* ao = xb;  // reuse x-bf16 buffer for attention output
  flash_gqa<<<dim3(16, 32), 256, 0, stream>>>(qkvb, vT, ao);

  gemm_bt<1><<<dim3(16, 32), 256, 0, stream>>>(ao, woT, bo, bo, bo, 1 << 30, 1 << 30,
                                               (float*)d_out, 4096, 2048, 2048);
}